// Round 4
// baseline (391.472 us; speedup 1.0000x reference)
//
// VQ layer (gumbel-softmax VQ) fused pipeline for MI355X (gfx950). Round 4.
//
//   K0a split_w : W_h, W_logits (512x512 f32) -> f16 hi/lo planes in ws
//   K0b split_x : X (65536x512 f32) -> f16 hi/lo planes in ws
//   K1  gemm3<0>: hiddens = relu(X @ Wh^T + bh) -> f16 hi/lo planes in codes half of d_out
//   K2  gemm3<1>: logits = hiddens @ Wl^T + bl -> d_out (f32)
//   K3  argmax  : z = logits + gumbel(u); codes[row,:] = codebook[argmax z,:]
//
// f32-GEMM emulation: a = hi + lo*2^-12 (f16 split, lo scaled by 2^12), using
// 3 MFMAs: hi.hi -> acc_hh ; hi.lo + lo.hi -> acc_mx ; D = acc_hh + acc_mx*2^-12.
//
// GEMM v3 (T3+T4 counted-vmcnt pipeline): 128x256 tile, 8 waves (512 thr,
// 64x64 out/wave, 2x2 of 32x32x16 f16 MFMA), BK=32, double-buffered LDS
// (2 x 48KB; A/B stored as 128B rows = [hi 64B | lo 64B], XOR ^((row&7)<<4)
// swizzle -> conflict-free b128 reads), raw s_barrier + counted
// s_waitcnt vmcnt(6) so prefetch loads stay in flight ACROSS barriers
// (never drain to 0 in the main loop). XCD-chunked block swizzle (1024%8==0).

#include <hip/hip_runtime.h>
#include <hip/hip_fp16.h>

typedef _Float16 h16;
typedef __attribute__((ext_vector_type(8))) _Float16 h16x8;
typedef __attribute__((ext_vector_type(4))) _Float16 h16x4;
typedef __attribute__((ext_vector_type(4))) float f32x4;
typedef __attribute__((ext_vector_type(16))) float f32x16;

#define KDIM 512
#define NDIM 512
#define LO_SCALE 4096.0f
#define LO_INV   0.000244140625f

__device__ __forceinline__ void gload16(const void* g, void* l) {
  __builtin_amdgcn_global_load_lds((const __attribute__((address_space(1))) void*)g,
                                   (__attribute__((address_space(3))) void*)l, 16, 0, 0);
}

#define WAITV(n) asm volatile("s_waitcnt vmcnt(" #n ")" ::: "memory")
#define WAITL0() asm volatile("s_waitcnt lgkmcnt(0)" ::: "memory")

// ---------------- K0a: split weights into f16 hi/lo planes ----------------
__global__ void split_w(const float* __restrict__ Wh, const float* __restrict__ Wl,
                        h16* __restrict__ WhHi, h16* __restrict__ WhLo,
                        h16* __restrict__ WlHi, h16* __restrict__ WlLo) {
  int i = blockIdx.x * 256 + threadIdx.x;          // 262144 elements
  float a = Wh[i];
  h16 h = (h16)a;
  WhHi[i] = h; WhLo[i] = (h16)((a - (float)h) * LO_SCALE);
  a = Wl[i];
  h = (h16)a;
  WlHi[i] = h; WlLo[i] = (h16)((a - (float)h) * LO_SCALE);
}

// ---------------- K0b: split inputs into f16 hi/lo planes ----------------
__global__ void split_x(const f32x4* __restrict__ X, h16x4* __restrict__ XHi,
                        h16x4* __restrict__ XLo) {
  int i = blockIdx.x * 256 + threadIdx.x;          // 8388608 f32x4 groups
  f32x4 a = X[i];
  h16x4 hv, lv;
#pragma unroll
  for (int j = 0; j < 4; ++j) {
    h16 h = (h16)a[j];
    hv[j] = h;
    lv[j] = (h16)((a[j] - (float)h) * LO_SCALE);
  }
  XHi[i] = hv; XLo[i] = lv;
}

// ====== GEMM v3: C[m,n] = sum_k A[m,k]*B[n,k] (+bias, epilogue) ======
// EPI 0: relu + split -> OHi/OLo planes (via LDS-packed coalesced store).
// EPI 1: f32 store to Cf32.
template <int EPI>
__launch_bounds__(512, 2)
__global__ void gemm3_k(const h16* __restrict__ AHi, const h16* __restrict__ ALo,
                        const h16* __restrict__ BHi, const h16* __restrict__ BLo,
                        const float* __restrict__ bias,
                        float* __restrict__ Cf32,
                        h16* __restrict__ OHi, h16* __restrict__ OLo) {
  // LDS: 2 stage buffers x 48KB = 96KB (A[128 rows][hi64|lo64]=16KB,
  // B[256 rows][hi64|lo64]=32KB); EPI0 epilogue reuses 128KB for repack.
  __shared__ __align__(16) char lds[131072];
  const int tid = threadIdx.x;
  const int wave = tid >> 6, lane = tid & 63;
  // XCD-chunked swizzle: 1024 wgs, 8 XCDs, 128 per XCD (bijective)
  const int wg = (blockIdx.x & 7) * 128 + (blockIdx.x >> 3);
  const int bm = wg >> 1, bn = wg & 1;             // 512 row-tiles x 2 col-tiles
  const int wm = wave >> 2, wn = wave & 3;         // 2x4 wave grid, 64x64/wave
  const long arow0 = (long)bm * 128;
  const int brow0 = bn * 256;

  f32x16 acc_hh[2][2] = {};
  f32x16 acc_mx[2][2] = {};

  // Stage K-step kt into buffer dbuf. LDS dest linear (wave-uniform base,
  // HW adds lane*16); source carries lane offset + XOR swizzle (granule
  // permutation within each 128B row; hi/lo plane selected per granule).
  // 6 gload16 per lane per stage -> vmcnt counts in units of 6.
#define STAGE(dbuf, kt)                                                       \
  {                                                                           \
    _Pragma("unroll")                                                         \
    for (int pass = 0; pass < 2; ++pass) {         /* A region: 16KB */       \
      int p = pass * 8192 + wave * 1024 + lane * 16;                          \
      int row = p >> 7;                                                       \
      int cb_ = (p ^ ((row & 7) << 4)) & 127;                                 \
      const char* srcp = (cb_ & 64) ? (const char*)ALo : (const char*)AHi;    \
      long off = (arow0 + row) * 1024 + (kt) * 64 + (cb_ & 63);               \
      gload16(srcp + off, (dbuf) + pass * 8192 + wave * 1024);                \
    }                                                                         \
    _Pragma("unroll")                                                         \
    for (int pass = 0; pass < 4; ++pass) {         /* B region: 32KB */       \
      int p = pass * 8192 + wave * 1024 + lane * 16;                          \
      int row = p >> 7;                                                       \
      int cb_ = (p ^ ((row & 7) << 4)) & 127;                                 \
      const char* srcp = (cb_ & 64) ? (const char*)BLo : (const char*)BHi;    \
      long off = (long)(brow0 + row) * 1024 + (kt) * 64 + (cb_ & 63);         \
      gload16(srcp + off, (dbuf) + 16384 + pass * 8192 + wave * 1024);        \
    }                                                                         \
  }

  STAGE(lds, 0);
  STAGE(lds + 49152, 1);

#pragma unroll
  for (int t = 0; t < 16; ++t) {
    // counted wait: own stage-t loads landed; stage-(t+1) stays in flight
    if (t < 15) { WAITV(6); } else { WAITV(0); }
    __builtin_amdgcn_sched_barrier(0);
    __builtin_amdgcn_s_barrier();                  // all waves' t-loads landed

    const char* buf = lds + (t & 1) * 49152;
    h16x8 ah[2][2], al[2][2], bh[2][2], bl[2][2];
#pragma unroll
    for (int ks = 0; ks < 2; ++ks)
#pragma unroll
      for (int i = 0; i < 2; ++i) {
        int ra = wm * 64 + i * 32 + (lane & 31);
        int hb = ra * 128 + ks * 32 + ((lane >> 5) << 4);
        int sw = (ra & 7) << 4;
        ah[ks][i] = *(const h16x8*)(buf + (hb ^ sw));
        al[ks][i] = *(const h16x8*)(buf + ((hb + 64) ^ sw));
        int rb = wn * 64 + i * 32 + (lane & 31);
        int hb2 = rb * 128 + ks * 32 + ((lane >> 5) << 4);
        int sw2 = (rb & 7) << 4;
        bh[ks][i] = *(const h16x8*)(buf + 16384 + (hb2 ^ sw2));
        bl[ks][i] = *(const h16x8*)(buf + 16384 + ((hb2 + 64) ^ sw2));
      }
#pragma unroll
    for (int ks = 0; ks < 2; ++ks)
#pragma unroll
      for (int i = 0; i < 2; ++i)
#pragma unroll
        for (int j = 0; j < 2; ++j)
          acc_hh[i][j] = __builtin_amdgcn_mfma_f32_32x32x16_f16(ah[ks][i], bh[ks][j], acc_hh[i][j], 0, 0, 0);
#pragma unroll
    for (int ks = 0; ks < 2; ++ks)
#pragma unroll
      for (int i = 0; i < 2; ++i)
#pragma unroll
        for (int j = 0; j < 2; ++j)
          acc_mx[i][j] = __builtin_amdgcn_mfma_f32_32x32x16_f16(ah[ks][i], bl[ks][j], acc_mx[i][j], 0, 0, 0);
#pragma unroll
    for (int ks = 0; ks < 2; ++ks)
#pragma unroll
      for (int i = 0; i < 2; ++i)
#pragma unroll
        for (int j = 0; j < 2; ++j)
          acc_mx[i][j] = __builtin_amdgcn_mfma_f32_32x32x16_f16(al[ks][i], bh[ks][j], acc_mx[i][j], 0, 0, 0);

    WAITL0();                                      // all LDS reads of buf done
    __builtin_amdgcn_s_barrier();                  // safe to overwrite buf
    __builtin_amdgcn_sched_barrier(0);
    if (t + 2 < 16) STAGE(lds + (t & 1) * 49152, t + 2);
  }
#undef STAGE

  // C/D layout (32x32, m74/m101): col = lane&31, row = (r&3)+8*(r>>2)+4*(lane>>5)
  if (EPI == 1) {
#pragma unroll
    for (int j = 0; j < 2; ++j) {
      int colg = bn * 256 + wn * 64 + j * 32 + (lane & 31);
      float bv = bias[colg];
#pragma unroll
      for (int i = 0; i < 2; ++i)
#pragma unroll
        for (int r = 0; r < 16; ++r) {
          long row = arow0 + wm * 64 + i * 32 + (r & 3) + 8 * (r >> 2) + 4 * (lane >> 5);
          Cf32[row * NDIM + colg] = acc_hh[i][j][r] + acc_mx[i][j][r] * LO_INV + bv;
        }
    }
  } else {
    // pack relu(v) as (hi | lo<<16) u32 into LDS [128][256], then coalesced
    // dual-plane 8-B stores. (All stage reads done: past final barrier.)
#pragma unroll
    for (int j = 0; j < 2; ++j) {
      int lcol = wn * 64 + j * 32 + (lane & 31);
      float bv = bias[bn * 256 + lcol];
#pragma unroll
      for (int i = 0; i < 2; ++i)
#pragma unroll
        for (int r = 0; r < 16; ++r) {
          int lrow = wm * 64 + i * 32 + (r & 3) + 8 * (r >> 2) + 4 * (lane >> 5);
          float v = fmaxf(acc_hh[i][j][r] + acc_mx[i][j][r] * LO_INV + bv, 0.0f);
          h16 h = (h16)v;
          h16 l = (h16)((v - (float)h) * LO_SCALE);
          unsigned uu = (unsigned)__builtin_bit_cast(unsigned short, h) |
                        ((unsigned)__builtin_bit_cast(unsigned short, l) << 16);
          *(unsigned*)(lds + lrow * 1024 + lcol * 4) = uu;
        }
    }
    __syncthreads();
#pragma unroll
    for (int pass = 0; pass < 16; ++pass) {
      int o = pass * 8192 + tid * 16;
      int lrow = o >> 10;                          // 1024-B packed rows
      int lcb = o & 1023;                          // u32-col byte offset
      uint4 d = *(const uint4*)(lds + o);
      uint2 hi, lo;
      hi.x = (d.x & 0xffffu) | (d.y << 16);
      hi.y = (d.z & 0xffffu) | (d.w << 16);
      lo.x = (d.x >> 16) | (d.y & 0xffff0000u);
      lo.y = (d.z >> 16) | (d.w & 0xffff0000u);
      long gb = (arow0 + lrow) * 1024 + bn * 512 + (lcb >> 1);
      *(uint2*)((char*)OHi + gb) = hi;
      *(uint2*)((char*)OLo + gb) = lo;
    }
  }
}

// ---- fallback GEMM (on-the-fly f32 split), only used if ws too small ----
__launch_bounds__(256, 2)
__global__ void gemm_fb(const float* __restrict__ Af32,
                        const h16* __restrict__ BHi, const h16* __restrict__ BLo,
                        const float* __restrict__ bias,
                        h16* __restrict__ OHi, h16* __restrict__ OLo) {
  __shared__ __align__(16) char lds[65536];
  const int tid = threadIdx.x;
  const int wave = tid >> 6, lane = tid & 63;
  const int bm = blockIdx.x >> 2, bn = blockIdx.x & 3;
  const int wm = wave >> 1, wn = wave & 1;
  const long arow0 = (long)bm * 128;
  const int brow0 = bn * 128;
  f32x4 acc_hh[4][4] = {};
  f32x4 acc_mx[4][4] = {};
  for (int kt = 0; kt < 8; ++kt) {
    const int kb = kt * 64;
#pragma unroll
    for (int pass = 0; pass < 8; ++pass) {
      int wb = pass * 4096 + wave * 1024;
      int p = wb + lane * 16;
      int row = p >> 8;
      int q = p ^ ((row & 15) << 4);
      long off = ((arow0 + row) * KDIM + kb) * 4 + (q & 255);
      gload16((const char*)Af32 + off, lds + wb);
    }
#pragma unroll
    for (int pass = 0; pass < 4; ++pass) {
      int wb = pass * 4096 + wave * 1024;
      int p = wb + lane * 16;
      int row = p >> 7;
      int q = p ^ ((row & 7) << 4);
      long off = ((long)(brow0 + row) * KDIM + kb) * 2 + (q & 127);
      gload16((const char*)BHi + off, lds + 32768 + wb);
      gload16((const char*)BLo + off, lds + 49152 + wb);
    }
    __syncthreads();
#pragma unroll
    for (int ks = 0; ks < 2; ++ks) {
      const int k0 = ks * 32 + (lane >> 4) * 8;
      h16x8 ah[4], al[4], bh[4], bl[4];
#pragma unroll
      for (int i = 0; i < 4; ++i) {
        int row = wm * 64 + i * 16 + (lane & 15);
        int b0 = (row * 256 + k0 * 4) ^ ((row & 15) << 4);
        int b1 = (row * 256 + k0 * 4 + 16) ^ ((row & 15) << 4);
        f32x4 u0 = *(const f32x4*)(lds + b0);
        f32x4 u1 = *(const f32x4*)(lds + b1);
#pragma unroll
        for (int t = 0; t < 4; ++t) {
          h16 h = (h16)u0[t];
          ah[i][t] = h; al[i][t] = (h16)((u0[t] - (float)h) * LO_SCALE);
        }
#pragma unroll
        for (int t = 0; t < 4; ++t) {
          h16 h = (h16)u1[t];
          ah[i][4 + t] = h; al[i][4 + t] = (h16)((u1[t] - (float)h) * LO_SCALE);
        }
      }
#pragma unroll
      for (int j = 0; j < 4; ++j) {
        int row = wn * 64 + j * 16 + (lane & 15);
        int byt = (row * 128 + k0 * 2) ^ ((row & 7) << 4);
        bh[j] = *(const h16x8*)(lds + 32768 + byt);
        bl[j] = *(const h16x8*)(lds + 49152 + byt);
      }
#pragma unroll
      for (int i = 0; i < 4; ++i)
#pragma unroll
        for (int j = 0; j < 4; ++j) {
          acc_hh[i][j] = __builtin_amdgcn_mfma_f32_16x16x32_f16(ah[i], bh[j], acc_hh[i][j], 0, 0, 0);
          acc_mx[i][j] = __builtin_amdgcn_mfma_f32_16x16x32_f16(ah[i], bl[j], acc_mx[i][j], 0, 0, 0);
          acc_mx[i][j] = __builtin_amdgcn_mfma_f32_16x16x32_f16(al[i], bh[j], acc_mx[i][j], 0, 0, 0);
        }
    }
    __syncthreads();
  }
#pragma unroll
  for (int j = 0; j < 4; ++j) {
    int col = bn * 128 + wn * 64 + j * 16 + (lane & 15);
    float bv = bias[col];
#pragma unroll
    for (int i = 0; i < 4; ++i) {
      long row = arow0 + wm * 64 + i * 16 + ((lane >> 4) * 4);
#pragma unroll
      for (int r = 0; r < 4; ++r) {
        float v = fmaxf(acc_hh[i][j][r] + acc_mx[i][j][r] * LO_INV + bv, 0.0f);
        long idx = (row + r) * (long)NDIM + col;
        h16 h = (h16)v;
        OHi[idx] = h;
        OLo[idx] = (h16)((v - (float)h) * LO_SCALE);
      }
    }
  }
}

// ---------------- K3: gumbel + argmax + codebook gather ----------------
__global__ void k3_argmax_gather(const float* __restrict__ logits,
                                 const float* __restrict__ u,
                                 const float* __restrict__ cb,
                                 const int* __restrict__ testing,
                                 float* __restrict__ codes) {
  const int wave = threadIdx.x >> 6, lane = threadIdx.x & 63;
  const long row = (long)blockIdx.x * 4 + wave;    // one wave per row
  const f32x4* lrow = (const f32x4*)(logits + row * 512);
  const f32x4* urow = (const f32x4*)(u + row * 512);
  const int test = *testing;

  float best = -3.4e38f;
  int bi = 0;
#pragma unroll
  for (int h = 0; h < 2; ++h) {
    int c4 = h * 64 + lane;
    f32x4 z = lrow[c4];
    if (!test) {
      f32x4 uu = urow[c4];
#pragma unroll
      for (int t = 0; t < 4; ++t)
        z[t] += -logf(-logf(uu[t] + 1e-20f) + 1e-20f);
    }
#pragma unroll
    for (int t = 0; t < 4; ++t) {                  // in-lane ascending indices
      int c = c4 * 4 + t;
      if (z[t] > best) { best = z[t]; bi = c; }
    }
  }
#pragma unroll
  for (int off = 32; off; off >>= 1) {             // max with min-index ties
    float ob = __shfl_xor(best, off);
    int oi = __shfl_xor(bi, off);
    if (ob > best || (ob == best && oi < bi)) { best = ob; bi = oi; }
  }
  const f32x4* src = (const f32x4*)(cb + (long)bi * 512);
  f32x4* dst = (f32x4*)(codes + row * 512);
  dst[lane] = src[lane];
  dst[lane + 64] = src[lane + 64];
}

// ---------------- host ----------------
extern "C" void kernel_launch(void* const* d_in, const int* in_sizes, int n_in,
                              void* d_out, int out_size, void* d_ws, size_t ws_size,
                              hipStream_t stream) {
  const float* X = (const float*)d_in[0];
  const float* Wh = (const float*)d_in[1];
  const float* bh = (const float*)d_in[2];
  const float* Wl = (const float*)d_in[3];
  const float* bl = (const float*)d_in[4];
  const float* cb = (const float*)d_in[5];
  const float* u = (const float*)d_in[6];
  const int* testing = (const int*)d_in[7];

  float* logits = (float*)d_out;                   // 33554432 f32
  float* codes = logits + 33554432;                // 33554432 f32
  // hiddens hi/lo f16 planes live in the codes region until K3 overwrites it
  h16* Hhi = (h16*)codes;
  h16* Hlo = Hhi + 33554432;

  h16* WhHi = (h16*)d_ws;                          // 4 x 0.5 MB weight planes
  h16* WhLo = WhHi + 262144;
  h16* WlHi = WhLo + 262144;
  h16* WlLo = WlHi + 262144;
  h16* Xhi = (h16*)((char*)d_ws + 2097152);        // 134 MB X planes
  h16* Xlo = Xhi + 33554432;
  const bool presplit = ws_size >= (size_t)2097152 + (size_t)134217728;

  split_w<<<dim3(1024), dim3(256), 0, stream>>>(Wh, Wl, WhHi, WhLo, WlHi, WlLo);

  if (presplit) {
    split_x<<<dim3(32768), dim3(256), 0, stream>>>((const f32x4*)X, (h16x4*)Xhi, (h16x4*)Xlo);
    gemm3_k<0><<<dim3(1024), dim3(512), 0, stream>>>(Xhi, Xlo, WhHi, WhLo, bh,
                                                     nullptr, Hhi, Hlo);
  } else {
    gemm_fb<<<dim3(2048), dim3(256), 0, stream>>>(X, WhHi, WhLo, bh, Hhi, Hlo);
  }
  gemm3_k<1><<<dim3(1024), dim3(512), 0, stream>>>(Hhi, Hlo, WlHi, WlLo, bl,
                                                   logits, nullptr, nullptr);

  k3_argmax_gather<<<dim3(16384), dim3(256), 0, stream>>>(logits, u, cb, testing, codes);
}

// Round 5
// 300.967 us; speedup vs baseline: 1.3007x; 1.3007x over previous
//
// VQ layer (gumbel-softmax VQ) fused pipeline for MI355X (gfx950). Round 5.
//
//   K0  split_w  : W_h, W_logits (512x512 f32) -> f16 hi/lo planes in ws (2 MB)
//   K1  gemm4<1,0>: hiddens = relu(X @ Wh^T + bh); A = f32 X staged to LDS and
//                   hi/lo-split in-register; output -> f16 hi/lo planes in the
//                   codes half of d_out (free until K3)
//   K2  gemm4<0,1>: logits = hiddens @ Wl^T + bl -> d_out (f32)
//   K3  argmax   : z = logits + gumbel(u); codes[row,:] = codebook[argmax z,:]
//
// f32-GEMM emulation: a = hi + lo*2^-12 (f16 split, lo scaled by 2^12), using
// 3 MFMAs: hi.hi -> acc_hh ; hi.lo + lo.hi -> acc_mx ; D = acc_hh + acc_mx*2^-12.
//
// GEMM v4: 128x128 tile, 4 waves (64x64 out/wave, 4x4 of 16x16x32 f16 MFMA —
// the 16-rows x 4-col-slot b128 read shape measured conflict-free in round 2;
// round 4's 32x32 fragments' 32-row shape cost 8.4M conflict cycles), BK=32,
// double-buffered LDS (2 x 32KB, 2 blocks/CU), counted s_waitcnt vmcnt(8) +
// raw s_barrier (prefetch stays in flight across barriers, T4), XOR-swizzled
// global_load_lds source (rule 21), XCD-chunked block swizzle (2048%8==0).

#include <hip/hip_runtime.h>
#include <hip/hip_fp16.h>

typedef _Float16 h16;
typedef __attribute__((ext_vector_type(8))) _Float16 h16x8;
typedef __attribute__((ext_vector_type(4))) float f32x4;

#define KDIM 512
#define NDIM 512
#define LO_SCALE 4096.0f
#define LO_INV   0.000244140625f

__device__ __forceinline__ void gload16(const void* g, void* l) {
  __builtin_amdgcn_global_load_lds((const __attribute__((address_space(1))) void*)g,
                                   (__attribute__((address_space(3))) void*)l, 16, 0, 0);
}

#define WAITV(n) asm volatile("s_waitcnt vmcnt(" #n ")" ::: "memory")
#define WAITL0() asm volatile("s_waitcnt lgkmcnt(0)" ::: "memory")

// ---------------- K0: split weights into f16 hi/lo planes ----------------
__global__ void split_w(const float* __restrict__ Wh, const float* __restrict__ Wl,
                        h16* __restrict__ WhHi, h16* __restrict__ WhLo,
                        h16* __restrict__ WlHi, h16* __restrict__ WlLo) {
  int i = blockIdx.x * 256 + threadIdx.x;          // 262144 elements
  float a = Wh[i];
  h16 h = (h16)a;
  WhHi[i] = h; WhLo[i] = (h16)((a - (float)h) * LO_SCALE);
  a = Wl[i];
  h = (h16)a;
  WlHi[i] = h; WlLo[i] = (h16)((a - (float)h) * LO_SCALE);
}

// ====== GEMM v4: C[m,n] = sum_k A[m,k]*B[n,k] (+bias, epilogue) ======
// AF32=1: A is f32, staged raw and split in-register after ds_read.
// AF32=0: A is presplit f16 hi/lo planes.
// EPI 0: relu + split -> OHi/OLo planes.  EPI 1: f32 -> Cf32.
// Both epilogues repack through LDS for fully-coalesced 16B/lane stores.
template <int AF32, int EPI>
__launch_bounds__(256, 2)
__global__ void gemm4_k(const void* __restrict__ Aptr, const void* __restrict__ AptrLo,
                        const h16* __restrict__ BHi, const h16* __restrict__ BLo,
                        const float* __restrict__ bias,
                        float* __restrict__ Cf32,
                        h16* __restrict__ OHi, h16* __restrict__ OLo) {
  // LDS: 2 stage buffers x 32KB. Per buffer:
  //   A region [0,16K):  AF32 ? [128 rows][128B f32] : [128 rows][hi64|lo64]
  //   B region [16K,32K): [128 rows][hi64|lo64]
  // 128-B rows, granule-XOR swizzle ^((row&7)<<4) applied on SOURCE (stage)
  // and on ds_read address (involution). Epilogue reuses all 64 KB.
  __shared__ __align__(16) char lds[65536];
  const int tid = threadIdx.x;
  const int wave = tid >> 6, lane = tid & 63;
  // XCD-chunked swizzle: 2048 wgs, 8 XCDs, 256 per XCD (bijective)
  const int wg = (blockIdx.x & 7) * 256 + (blockIdx.x >> 3);
  const int bm = wg >> 2, bn = wg & 3;             // 512 row-tiles x 4 col-tiles
  const int wm = wave >> 1, wn = wave & 1;         // 2x2 wave grid, 64x64/wave
  const long arow0 = (long)bm * 128;
  const int brow0 = bn * 128;
  const int q = lane >> 4, rlo = lane & 15;

  f32x4 acc_hh[4][4] = {};
  f32x4 acc_mx[4][4] = {};

  // Stage K-step kt into buffer at bufoff. LDS dest linear (wave-uniform
  // base; HW adds lane*16); source address carries the lane offset + XOR
  // granule swizzle + plane select. 8 gload16 per lane per stage.
#define STAGE4(bufoff, kt)                                                    \
  {                                                                           \
    _Pragma("unroll")                                                         \
    for (int pass = 0; pass < 4; ++pass) {         /* A region: 16KB */       \
      int p = pass * 4096 + wave * 1024 + lane * 16;                          \
      int row = p >> 7;                                                       \
      int gs = ((p >> 4) & 7) ^ (row & 7);                                    \
      if (AF32) {                                                             \
        long off = (arow0 + row) * 2048 + (kt) * 128 + gs * 16;               \
        gload16((const char*)Aptr + off,                                      \
                lds + (bufoff) + pass * 4096 + wave * 1024);                  \
      } else {                                                                \
        const char* sp = (gs & 4) ? (const char*)AptrLo : (const char*)Aptr;  \
        long off = (arow0 + row) * 1024 + (kt) * 64 + (gs & 3) * 16;          \
        gload16(sp + off, lds + (bufoff) + pass * 4096 + wave * 1024);        \
      }                                                                       \
    }                                                                         \
    _Pragma("unroll")                                                         \
    for (int pass = 0; pass < 4; ++pass) {         /* B region: 16KB */       \
      int p = pass * 4096 + wave * 1024 + lane * 16;                          \
      int row = p >> 7;                                                       \
      int gs = ((p >> 4) & 7) ^ (row & 7);                                    \
      const char* sp = (gs & 4) ? (const char*)BLo : (const char*)BHi;        \
      long off = (long)(brow0 + row) * 1024 + (kt) * 64 + (gs & 3) * 16;      \
      gload16(sp + off, lds + (bufoff) + 16384 + pass * 4096 + wave * 1024);  \
    }                                                                         \
  }

  STAGE4(0, 0);
  STAGE4(32768, 1);

#pragma unroll
  for (int t = 0; t < 16; ++t) {
    // counted wait: stage-t loads (oldest 8) landed; stage-(t+1) in flight
    if (t < 15) { WAITV(8); } else { WAITV(0); }
    __builtin_amdgcn_sched_barrier(0);
    __builtin_amdgcn_s_barrier();                  // all waves' t-loads landed
    __builtin_amdgcn_sched_barrier(0);

    const char* buf = lds + (t & 1) * 32768;
    h16x8 ah[4], al[4], bh[4], bl[4];
#pragma unroll
    for (int i = 0; i < 4; ++i) {
      int row = wm * 64 + i * 16 + rlo;
      int sw = (row & 7) << 4;
      if (AF32) {
        f32x4 u0 = *(const f32x4*)(buf + row * 128 + ((q * 32) ^ sw));
        f32x4 u1 = *(const f32x4*)(buf + row * 128 + ((q * 32 + 16) ^ sw));
#pragma unroll
        for (int e = 0; e < 4; ++e) {
          h16 h = (h16)u0[e];
          ah[i][e] = h; al[i][e] = (h16)((u0[e] - (float)h) * LO_SCALE);
          h16 h2 = (h16)u1[e];
          ah[i][4 + e] = h2; al[i][4 + e] = (h16)((u1[e] - (float)h2) * LO_SCALE);
        }
      } else {
        ah[i] = *(const h16x8*)(buf + row * 128 + ((q * 16) ^ sw));
        al[i] = *(const h16x8*)(buf + row * 128 + ((q * 16 + 64) ^ sw));
      }
      int rb = wn * 64 + i * 16 + rlo;
      int swb = (rb & 7) << 4;
      bh[i] = *(const h16x8*)(buf + 16384 + rb * 128 + ((q * 16) ^ swb));
      bl[i] = *(const h16x8*)(buf + 16384 + rb * 128 + ((q * 16 + 64) ^ swb));
    }
#pragma unroll
    for (int i = 0; i < 4; ++i)
#pragma unroll
      for (int j = 0; j < 4; ++j)
        acc_hh[i][j] = __builtin_amdgcn_mfma_f32_16x16x32_f16(ah[i], bh[j], acc_hh[i][j], 0, 0, 0);
#pragma unroll
    for (int i = 0; i < 4; ++i)
#pragma unroll
      for (int j = 0; j < 4; ++j)
        acc_mx[i][j] = __builtin_amdgcn_mfma_f32_16x16x32_f16(ah[i], bl[j], acc_mx[i][j], 0, 0, 0);
#pragma unroll
    for (int i = 0; i < 4; ++i)
#pragma unroll
      for (int j = 0; j < 4; ++j)
        acc_mx[i][j] = __builtin_amdgcn_mfma_f32_16x16x32_f16(al[i], bh[j], acc_mx[i][j], 0, 0, 0);

    WAITL0();                                      // our reads of buf done
    __builtin_amdgcn_sched_barrier(0);
    __builtin_amdgcn_s_barrier();                  // safe to overwrite buf
    __builtin_amdgcn_sched_barrier(0);
    if (t + 2 < 16) STAGE4((t & 1) * 32768, t + 2);
  }
#undef STAGE4

  // ---- epilogue. C/D layout (16x16, m89): col=lane&15, row=(lane>>4)*4+r.
  // Repack tile through LDS (stage buffers dead), then coalesced stores.
#pragma unroll
  for (int j = 0; j < 4; ++j) {
    int lcol = wn * 64 + j * 16 + rlo;
    float bv = bias[bn * 128 + lcol];
#pragma unroll
    for (int i = 0; i < 4; ++i)
#pragma unroll
      for (int r = 0; r < 4; ++r) {
        int lrow = wm * 64 + i * 16 + q * 4 + r;
        float v = acc_hh[i][j][r] + acc_mx[i][j][r] * LO_INV + bv;
        if (EPI == 0) {
          v = fmaxf(v, 0.0f);
          h16 h = (h16)v;
          h16 l = (h16)((v - (float)h) * LO_SCALE);
          unsigned uu = (unsigned)__builtin_bit_cast(unsigned short, h) |
                        ((unsigned)__builtin_bit_cast(unsigned short, l) << 16);
          *(unsigned*)(lds + lrow * 512 + lcol * 4) = uu;
        } else {
          *(float*)(lds + lrow * 512 + lcol * 4) = v;
        }
      }
  }
  __syncthreads();
#pragma unroll
  for (int pass = 0; pass < 16; ++pass) {
    int o = pass * 4096 + tid * 16;
    int lrow = o >> 9;                             // 512-B packed rows
    int lcb = o & 511;
    if (EPI == 0) {
      uint4 d = *(const uint4*)(lds + o);
      uint2 hi, lo;
      hi.x = (d.x & 0xffffu) | (d.y << 16);
      hi.y = (d.z & 0xffffu) | (d.w << 16);
      lo.x = (d.x >> 16) | (d.y & 0xffff0000u);
      lo.y = (d.z >> 16) | (d.w & 0xffff0000u);
      long gb = (arow0 + lrow) * 1024 + bn * 256 + (lcb >> 1);
      *(uint2*)((char*)OHi + gb) = hi;
      *(uint2*)((char*)OLo + gb) = lo;
    } else {
      f32x4 d = *(const f32x4*)(lds + o);
      long gb = (arow0 + lrow) * 2048 + bn * 512 + lcb;
      *(f32x4*)((char*)Cf32 + gb) = d;
    }
  }
}

// ---------------- K3: gumbel + argmax + codebook gather ----------------
__global__ void k3_argmax_gather(const float* __restrict__ logits,
                                 const float* __restrict__ u,
                                 const float* __restrict__ cb,
                                 const int* __restrict__ testing,
                                 float* __restrict__ codes) {
  const int wave = threadIdx.x >> 6, lane = threadIdx.x & 63;
  const long row = (long)blockIdx.x * 4 + wave;    // one wave per row
  const f32x4* lrow = (const f32x4*)(logits + row * 512);
  const f32x4* urow = (const f32x4*)(u + row * 512);
  const int test = *testing;

  float best = -3.4e38f;
  int bi = 0;
#pragma unroll
  for (int h = 0; h < 2; ++h) {
    int c4 = h * 64 + lane;
    f32x4 z = lrow[c4];
    if (!test) {
      f32x4 uu = urow[c4];
#pragma unroll
      for (int t = 0; t < 4; ++t)
        z[t] += -logf(-logf(uu[t] + 1e-20f) + 1e-20f);
    }
#pragma unroll
    for (int t = 0; t < 4; ++t) {                  // in-lane ascending indices
      int c = c4 * 4 + t;
      if (z[t] > best) { best = z[t]; bi = c; }
    }
  }
#pragma unroll
  for (int off = 32; off; off >>= 1) {             // max with min-index ties
    float ob = __shfl_xor(best, off);
    int oi = __shfl_xor(bi, off);
    if (ob > best || (ob == best && oi < bi)) { best = ob; bi = oi; }
  }
  const f32x4* src = (const f32x4*)(cb + (long)bi * 512);
  f32x4* dst = (f32x4*)(codes + row * 512);
  dst[lane] = src[lane];
  dst[lane + 64] = src[lane + 64];
}

// ---------------- host ----------------
extern "C" void kernel_launch(void* const* d_in, const int* in_sizes, int n_in,
                              void* d_out, int out_size, void* d_ws, size_t ws_size,
                              hipStream_t stream) {
  const float* X = (const float*)d_in[0];
  const float* Wh = (const float*)d_in[1];
  const float* bh = (const float*)d_in[2];
  const float* Wl = (const float*)d_in[3];
  const float* bl = (const float*)d_in[4];
  const float* cb = (const float*)d_in[5];
  const float* u = (const float*)d_in[6];
  const int* testing = (const int*)d_in[7];

  float* logits = (float*)d_out;                   // 33554432 f32
  float* codes = logits + 33554432;                // 33554432 f32
  // hiddens hi/lo f16 planes live in the codes region until K3 overwrites it
  h16* Hhi = (h16*)codes;
  h16* Hlo = Hhi + 33554432;

  h16* WhHi = (h16*)d_ws;                          // 4 x 0.5 MB weight planes
  h16* WhLo = WhHi + 262144;
  h16* WlHi = WhLo + 262144;
  h16* WlLo = WlHi + 262144;

  split_w<<<dim3(1024), dim3(256), 0, stream>>>(Wh, Wl, WhHi, WhLo, WlHi, WlLo);

  gemm4_k<1, 0><<<dim3(2048), dim3(256), 0, stream>>>(
      (const void*)X, nullptr, WhHi, WhLo, bh, nullptr, Hhi, Hlo);
  gemm4_k<0, 1><<<dim3(2048), dim3(256), 0, stream>>>(
      (const void*)Hhi, (const void*)Hlo, WlHi, WlLo, bl, logits, nullptr, nullptr);

  k3_argmax_gather<<<dim3(16384), dim3(256), 0, stream>>>(logits, u, cb, testing, codes);
}